// Round 12
// baseline (230.571 us; speedup 1.0000x reference)
//
#include <hip/hip_runtime.h>
#include <hip/hip_bf16.h>

// Problem constants
#define B_SZ 8
#define L_SZ 2048
#define DM   512
#define HIDC 1024            // complex hidden channels
#define NROW (B_SZ*L_SZ)     // 16384
#define NCOL (2*HIDC)        // 2048 (interleaved: col 2d = re_d, 2d+1 = im_d)
#define LCH  128             // scan chunk length
#define NCH  (L_SZ/LCH)      // 16 chunks

typedef __attribute__((ext_vector_type(8))) short bf16x8;
typedef __attribute__((ext_vector_type(4))) float f32x4;

typedef __attribute__((address_space(1))) const void gvoid_t;
typedef __attribute__((address_space(3))) void lvoid_t;

__device__ __forceinline__ void gload_lds16(const void* g, void* l) {
  __builtin_amdgcn_global_load_lds((gvoid_t*)g, (lvoid_t*)l, 16, 0, 0);
}

__device__ __forceinline__ unsigned short f2bf(float v) {
  return __builtin_bit_cast(unsigned short, __float2bfloat16(v));
}
__device__ __forceinline__ float bf2f(unsigned short u) {
  return __bfloat162float(__builtin_bit_cast(__hip_bfloat16, u));
}

// h_local(bf16 u32) + g * (Lambda(bf16 u32) (*) P(f32 pair)) -> bf16 u32
__device__ __forceinline__ unsigned int corr1(unsigned int h, unsigned int l,
                                              float pr, float pi, float g) {
  float hr = bf2f((unsigned short)(h & 0xffffu)), hi = bf2f((unsigned short)(h >> 16));
  float lr = bf2f((unsigned short)(l & 0xffffu)), li = bf2f((unsigned short)(l >> 16));
  float cr = g * (lr * pr - li * pi);
  float ci = g * (lr * pi + li * pr);
  return (unsigned int)f2bf(hr + cr) | ((unsigned int)f2bf(hi + ci) << 16);
}

// ---------------- merged prep kernel (x-cvt REMOVED: folded into GEMM1) ----------------
__global__ void k_prep(const float* __restrict__ Wr,  const float* __restrict__ Wi,
                       const float* __restrict__ br,  const float* __restrict__ bi,
                       const float* __restrict__ gamma_log,
                       const float* __restrict__ Wor, const float* __restrict__ Woi,
                       const float* __restrict__ nu_log, const float* __restrict__ theta_log,
                       const float* __restrict__ mask,
                       unsigned short* __restrict__ W1b, float* __restrict__ b1,
                       unsigned short* __restrict__ W2b, float* __restrict__ lam,
                       unsigned int* __restrict__ Lt, float* __restrict__ Gm) {
  int bid = blockIdx.x, t = threadIdx.x;
  if (bid < 4096) {                       // W1b[n][k], n=2d(+1)
    long idx = (long)bid * 256 + t;       // 2048*512
    int n = (int)(idx >> 9), k = (int)(idx & 511);
    int d = n >> 1;
    float g = __expf(gamma_log[d]);
    float w = (n & 1) ? Wi[(long)d * DM + k] : Wr[(long)d * DM + k];
    W1b[idx] = f2bf(g * w);
    if (k == 0) b1[n] = g * ((n & 1) ? bi[d] : br[d]);
  } else if (bid < 8192) {                // W2b[e][k], k=2d / 2d+1
    long idx = (long)(bid - 4096) * 256 + t; // 512*2048
    int e = (int)(idx >> 11), k = (int)(idx & 2047);
    int d = k >> 1;
    float w = (k & 1) ? -Woi[(long)e * HIDC + d] : Wor[(long)e * HIDC + d];
    W2b[idx] = f2bf(w);
  } else if (bid < 8196) {                // lam + Lambda table
    int d = (bid - 8192) * 256 + t;
    if (d < HIDC) {
      float nu = __expf(nu_log[d]);
      float th = __expf(theta_log[d]);
      float mag = __expf(-nu);
      float lr = mag * cosf(th), li = mag * sinf(th);
      lam[d]        = lr;
      lam[HIDC + d] = li;
      float ar = lr, ai = li;             // lam^{j+1}, j = 0..127
      for (int j = 0; j < 128; j++) {
        Lt[j * 1024 + d] = (unsigned int)f2bf(ar) | ((unsigned int)f2bf(ai) << 16);
        float nr = ar * lr - ai * li, ni = ar * li + ai * lr;
        ar = nr; ai = ni;
      }
    }
  } else {                                // Gm[b][l]
    if (t < 128) {
      int bb = t >> 4, cc = t & 15;
      int base2 = bb * 2048 + cc * 128;
      float G = (cc == 0) ? 0.f : mask[base2 - 1];
      Gm[base2] = G;
#pragma unroll 8
      for (int j = 1; j < 128; j++) {
        G *= mask[base2 + j - 1];
        Gm[base2 + j] = G;
      }
    }
  }
}

// ============ GEMM1 v6: fp32-A reg-staged (cvt folded in) + local-scan epilogue ============
// A = x (fp32, converted to bf16 in flight); B = W1b (bf16, gload_lds).
// BM=256 BN=128 BK=32, 4 waves, triple-buffered LDS, counted vmcnt(10).
// Ledger: issue order per iter t: B(t+2)[2 gload_lds] then A(t+2)[8 float4];
//  - vmcnt(10) after MFMA(t) retires everything except the newest 10
//    (= B(t+2)+A(t+2)) => A(t+1) regs and B(t+1) LDS are ready.
//  - ACVT writes Abuf (t+1)%3 whose last readers (tile t-2) finished before
//    the barrier ending iter t-2. BISSUE targets Bbuf (t+2)%3 = (t-1)%3,
//    read only in iter t-1, done before its closing barrier.
//  - lgkmcnt(0) drains ds_writes before the barrier publishes Abuf(t+1).
//  - tail: t+2>=NT -> vmcnt(0).
// Swizzle: ds_write slot = (tid&3)^((srow>>1)&3) (direct write-side), read
// slot = lq^((fr>>1)&3) -- identical involution to the proven v5 core.
__global__ __launch_bounds__(256, 2)
void gemm1_fused(const float* __restrict__ X, const unsigned short* __restrict__ Bw,
                 unsigned short* __restrict__ C, const float* __restrict__ bias,
                 const float* __restrict__ lam, const float* __restrict__ mask,
                 float2* __restrict__ E2) {
  constexpr int K = DM, N = NCOL;         // 512, 2048
  constexpr int ABUF = 256 * 32, BBUF = 128 * 32, NT = K / 32;  // NT=16
  extern __shared__ unsigned short lds[];
  unsigned short* As = lds;               // 3 * ABUF
  unsigned short* Bs = lds + 3 * ABUF;    // 3 * BBUF

  const int tid  = threadIdx.x;
  const int w    = tid >> 6, lane = tid & 63;
  const int wr   = w >> 1,   wc   = w & 1;
  const int fr   = lane & 15, lq  = lane >> 4;

  // XCD 2-D blocking: 1024 blocks = 64 mt x 16 nt, XCD owns 8 mt x all nt
  const int xcd  = blockIdx.x & 7;
  const int idx  = blockIdx.x >> 3;
  const int mt   = xcd * 8 + (idx >> 4);
  const int nt   = idx & 15;
  const long m0  = (long)mt * 256;
  const long n0  = (long)nt * 128;
  const int rot  = ((blockIdx.x >> 8) & 1) << 3;   // anti-phase K order

  // B staging (pre-swizzled source, linear gload_lds dest) -- unchanged
  const int srow  = tid >> 2;                       // 0..63
  const int gslot = (tid & 3) ^ ((tid >> 3) & 3);
  const unsigned short* Bgp = Bw + (n0 + srow) * (long)K + gslot * 8;
  const int ldst = tid * 8;

  // A reg-staging: thread covers rows {srow + 64u}, fp32 cols (tid&3)*8..+8
  const float* Xgp = X + (m0 + srow) * (long)K + (tid & 3) * 8;
  const int aswz = ((tid & 3) ^ ((tid >> 3) & 3)) << 3;   // swizzled slot, ushorts
  const int arow32 = srow * 32;

#define BISSUE(t, b) {                                                       \
    long ko = (long)(((t) + rot) & (NT - 1)) * 32;                           \
    gload_lds16(Bgp + ko,                &Bs[(b) * BBUF +        ldst]);     \
    gload_lds16(Bgp + ko + (long)64 * K, &Bs[(b) * BBUF + 2048 + ldst]); }

  float4 S0_a0, S0_b0, S0_a1, S0_b1, S0_a2, S0_b2, S0_a3, S0_b3;
  float4 S1_a0, S1_b0, S1_a1, S1_b1, S1_a2, S1_b2, S1_a3, S1_b3;

#define AISSUE(P, t) {                                                       \
    long ko = (long)(((t) + rot) & (NT - 1)) * 32;                           \
    P##_a0 = *(const float4*)(Xgp + ko);                                     \
    P##_b0 = *(const float4*)(Xgp + ko + 4);                                 \
    P##_a1 = *(const float4*)(Xgp + ko + (long)64 * K);                      \
    P##_b1 = *(const float4*)(Xgp + ko + (long)64 * K + 4);                  \
    P##_a2 = *(const float4*)(Xgp + ko + (long)128 * K);                     \
    P##_b2 = *(const float4*)(Xgp + ko + (long)128 * K + 4);                 \
    P##_a3 = *(const float4*)(Xgp + ko + (long)192 * K);                     \
    P##_b3 = *(const float4*)(Xgp + ko + (long)192 * K + 4); }

#define CVT8(dst, f0, f1) {                                                  \
    uint4 o;                                                                 \
    o.x = (unsigned)f2bf(f0.x) | ((unsigned)f2bf(f0.y) << 16);               \
    o.y = (unsigned)f2bf(f0.z) | ((unsigned)f2bf(f0.w) << 16);               \
    o.z = (unsigned)f2bf(f1.x) | ((unsigned)f2bf(f1.y) << 16);               \
    o.w = (unsigned)f2bf(f1.z) | ((unsigned)f2bf(f1.w) << 16);               \
    *(uint4*)(dst) = o; }

#define ACVT(P, b) {                                                         \
    CVT8(&As[(b) * ABUF + (0 * 2048) + arow32 + aswz], P##_a0, P##_b0);      \
    CVT8(&As[(b) * ABUF + (1 * 2048) + arow32 + aswz], P##_a1, P##_b1);      \
    CVT8(&As[(b) * ABUF + (2 * 2048) + arow32 + aswz], P##_a2, P##_b2);      \
    CVT8(&As[(b) * ABUF + (3 * 2048) + arow32 + aswz], P##_a3, P##_b3); }

  const int sx = (lq ^ ((fr >> 1) & 3)) << 3;
  f32x4 acc[8][4] = {};

#define MMSTEP(b) {                                                          \
    const unsigned short* Ab = As + (b) * ABUF;                              \
    const unsigned short* Bb = Bs + (b) * BBUF;                              \
    bf16x8 fa[8], fb[4];                                                     \
    _Pragma("unroll")                                                        \
    for (int m = 0; m < 8; m++)                                              \
      fa[m] = *(const bf16x8*)&Ab[(wr * 128 + m * 16 + fr) * 32 + sx];       \
    _Pragma("unroll")                                                        \
    for (int n = 0; n < 4; n++)                                              \
      fb[n] = *(const bf16x8*)&Bb[(wc * 64 + n * 16 + fr) * 32 + sx];        \
    __builtin_amdgcn_s_setprio(1);                                           \
    _Pragma("unroll")                                                        \
    for (int m = 0; m < 8; m++)                                              \
      _Pragma("unroll")                                                      \
      for (int n = 0; n < 4; n++)                                            \
        acc[m][n] = __builtin_amdgcn_mfma_f32_16x16x32_bf16(fa[m], fb[n], acc[m][n], 0, 0, 0); \
    __builtin_amdgcn_s_setprio(0); }

#define STEP(t, cbv, b2v, LS, CS) {                                          \
    if ((t) + 2 < NT) { BISSUE((t) + 2, b2v); AISSUE(LS, (t) + 2); }         \
    MMSTEP(cbv);                                                             \
    if ((t) < NT - 1) {                                                      \
      if ((t) + 2 < NT) { asm volatile("s_waitcnt vmcnt(10)" ::: "memory"); }\
      else              { asm volatile("s_waitcnt vmcnt(0)"  ::: "memory"); }\
      ACVT(CS, ((cbv) == 2) ? 0 : (cbv) + 1);                                \
      asm volatile("s_waitcnt lgkmcnt(0)" ::: "memory");                     \
      __builtin_amdgcn_s_barrier();                                          \
      __builtin_amdgcn_sched_barrier(0);                                     \
    } }

  // prologue: B(0),A(0),B(1),A(1); vmcnt(10) retires B0+A0; cvt A0 -> Abuf0
  BISSUE(0, 0); AISSUE(S0, 0);
  BISSUE(1, 1); AISSUE(S1, 1);
  asm volatile("s_waitcnt vmcnt(10)" ::: "memory");
  ACVT(S0, 0);
  asm volatile("s_waitcnt lgkmcnt(0)" ::: "memory");
  __builtin_amdgcn_s_barrier();
  __builtin_amdgcn_sched_barrier(0);

  int cb = 0, b2 = 2;
  for (int t = 0; t < NT; t += 2) {
    STEP(t, cb, b2, S0, S1);
    cb = (cb == 2) ? 0 : cb + 1; b2 = (b2 == 2) ? 0 : b2 + 1;
    STEP(t + 1, cb, b2, S1, S0);
    cb = (cb == 2) ? 0 : cb + 1; b2 = (b2 == 2) ? 0 : b2 + 1;
  }
#undef STEP
#undef MMSTEP
#undef ACVT
#undef CVT8
#undef AISSUE
#undef BISSUE

  // ---- epilogue 1: bias-add, write bf16 tile to LDS [256][pitch 132]
  __syncthreads();
  const int cr0 = lq * 4, cc = fr;
#pragma unroll
  for (int m = 0; m < 8; m++) {
#pragma unroll
    for (int n = 0; n < 4; n++) {
      int coll = wc * 64 + n * 16 + cc;
      float bv = bias[n0 + coll];
#pragma unroll
      for (int r = 0; r < 4; r++) {
        int rowl = wr * 128 + m * 16 + cr0 + r;
        lds[rowl * 132 + coll] = f2bf(acc[m][n][r] + bv);
      }
    }
  }
  __syncthreads();

  // ---- preload mask slice to LDS scratch (after the tile)
  const int bidx = (int)(m0 >> 11);
  const int l0   = (int)(m0 & 2047);
  float* mbuf = (float*)(lds + 256 * 132);   // 256 floats
  mbuf[tid] = mask[bidx * L_SZ + l0 + tid];
  __syncthreads();

  // ---- epilogue 2: full local scan (128 threads)
  if (tid < 128) {
    const int chunk = tid >> 6, ch = tid & 63;
    const int dglob = (int)(n0 >> 1) + ch;
    const int cglob = (l0 >> 7) + chunk;
    const float lr = lam[dglob], li = lam[HIDC + dglob];
    const unsigned int* ldsw = (const unsigned int*)lds;
    unsigned int* Cw = (unsigned int*)C;
    const long crow0 = (m0 + chunk * 128) * (N / 2) + (n0 >> 1) + ch;
    float hr = 0.f, hi = 0.f;
    unsigned int v = ldsw[(chunk * 128) * 66 + ch];
    for (int j = 0; j < 128; j++) {
      unsigned int vn = (j < 127) ? ldsw[(chunk * 128 + j + 1) * 66 + ch] : 0u;
      float xr = bf2f((unsigned short)(v & 0xffffu));
      float xi = bf2f((unsigned short)(v >> 16));
      float g = (j > 0) ? mbuf[chunk * 128 + j - 1] : 0.f;   // chunk-local init
      float nr = xr + g * (lr * hr - li * hi);
      float ni = xi + g * (lr * hi + li * hr);
      hr = nr; hi = ni;
      Cw[crow0 + (long)j * (N / 2)] =
          (unsigned int)f2bf(hr) | ((unsigned int)f2bf(hi) << 16);
      v = vn;
    }
    E2[((long)bidx * NCH + cglob) * HIDC + dglob] = make_float2(hr, hi);
  }
}

// -------- scan pass 2: chunk-carry scan over E --------
__global__ void k_scan_carry(const float2* __restrict__ E2, const float* __restrict__ lam,
                             float2* __restrict__ P2) {
  int idx = blockIdx.x * 256 + threadIdx.x;   // 8192 = B * HIDC
  int b = idx >> 10, d = idx & (HIDC - 1);
  float lr = lam[d], li = lam[HIDC + d];
  float ar = lr, ai = li;                     // lam^128 via 7 squarings
  for (int s = 0; s < 7; s++) { float nr = ar * ar - ai * ai; float ni = 2.f * ar * ai; ar = nr; ai = ni; }
  float pr = 0.f, pi = 0.f;
  for (int c = 0; c < NCH; c++) {
    P2[((long)b * NCH + c) * HIDC + d] = make_float2(pr, pi);
    float2 e = E2[((long)b * NCH + c) * HIDC + d];
    float nr = e.x + ar * pr - ai * pi;
    float ni = e.y + ar * pi + ai * pr;
    pr = nr; pi = ni;
  }
}

// -------- carry correction (streaming, in place): h = h_local + Gm*(Lt (*) P) --------
__global__ __launch_bounds__(256)
void k_corr(unsigned int* __restrict__ u, const unsigned int* __restrict__ Lt,
            const float2* __restrict__ P2, const float* __restrict__ Gm) {
  const int t = threadIdx.x;
  const long row = (long)blockIdx.x * 2 + (t >> 7);
  const int d0 = (t & 127) * 8;
  const int j  = (int)(row & 127);
  const long bc = row >> 7;               // b*16 + c
  const float g = Gm[row];
  unsigned int* up = u + row * 1024 + d0;
  const unsigned int* lp = Lt + (long)j * 1024 + d0;
  const float2* pp = P2 + bc * 1024 + d0;
  uint4 h0 = *(const uint4*)up,        h1 = *(const uint4*)(up + 4);
  uint4 l0 = *(const uint4*)lp,        l1 = *(const uint4*)(lp + 4);
  float4 p0 = *(const float4*)pp,       p1 = *(const float4*)(pp + 2);
  float4 p2 = *(const float4*)(pp + 4), p3 = *(const float4*)(pp + 6);
  uint4 o0, o1;
  o0.x = corr1(h0.x, l0.x, p0.x, p0.y, g);
  o0.y = corr1(h0.y, l0.y, p0.z, p0.w, g);
  o0.z = corr1(h0.z, l0.z, p1.x, p1.y, g);
  o0.w = corr1(h0.w, l0.w, p1.z, p1.w, g);
  o1.x = corr1(h1.x, l1.x, p2.x, p2.y, g);
  o1.y = corr1(h1.y, l1.y, p2.z, p2.w, g);
  o1.z = corr1(h1.z, l1.z, p3.x, p3.y, g);
  o1.w = corr1(h1.w, l1.w, p3.z, p3.w, g);
  *(uint4*)up = o0;
  *(uint4*)(up + 4) = o1;
}

// ============ GEMM2: 8-phase counted-vmcnt schedule (R11, verified) ============
// resid now read directly from fp32 x.
__global__ __launch_bounds__(512, 1)
void gemm2_8ph(const unsigned short* __restrict__ A, const unsigned short* __restrict__ Bw,
               float* __restrict__ Out, const float* __restrict__ bias,
               const float* __restrict__ resid) {
  constexpr int K = NCOL, N = DM, NT = K / 64;   // 2048, 512, 32
  constexpr int ABUF = 256 * 64;   // 16384 ushorts (32KB)
  constexpr int BBUF = 128 * 64;   // 8192 ushorts (16KB)
  extern __shared__ unsigned short lds[];
  unsigned short* As = lds;              // 3 * ABUF
  unsigned short* Bs = lds + 3 * ABUF;   // 3 * BBUF

  const int tid = threadIdx.x;
  const int w = tid >> 6, lane = tid & 63;
  const int wr = w >> 2, wc = w & 3;     // 2M x 4N wave grid
  const int fr = lane & 15, lq = lane >> 4;

  // 256 blocks = 64 mt x 4 nt; XCD owns 8 mt x all nt
  const int xcd = blockIdx.x & 7;
  const int idx = blockIdx.x >> 3;       // 0..31
  const int mt  = xcd * 8 + (idx >> 2);
  const int nt  = idx & 3;
  const long m0 = (long)mt * 256, n0 = (long)nt * 128;

  // staging: 512 thr x 16B = 8KB = 64 rows(128B) per granule
  const int srow  = tid >> 3;            // 0..63
  const int gslot = (tid & 7) ^ ((tid >> 3) & 7);
  const unsigned short* Agp = A  + (m0 + srow) * (long)K + gslot * 8;
  const unsigned short* Bgp = Bw + (n0 + srow) * (long)K + gslot * 8;
  const int ldst = tid * 8;

#define SAG(t, b, g) gload_lds16(Agp + (long)(t) * 64 + (long)((g) * 64) * K, \
                                 &As[(b) * ABUF + (g) * 4096 + ldst])
#define SBG(t, b, g) gload_lds16(Bgp + (long)(t) * 64 + (long)((g) * 64) * K, \
                                 &Bs[(b) * BBUF + (g) * 4096 + ldst])

  const int sx0 = ((0 + lq) ^ (fr & 7)) << 3;
  const int sx1 = ((4 + lq) ^ (fr & 7)) << 3;

  bf16x8 fa[2][2], fb[2][2];
  f32x4 acc[8][2] = {};

#define LDFB(b) { _Pragma("unroll")                                           \
    for (int n = 0; n < 2; n++) {                                             \
      fb[n][0] = *(const bf16x8*)&Bs[(b)*BBUF + (wc*32 + n*16 + fr)*64 + sx0];\
      fb[n][1] = *(const bf16x8*)&Bs[(b)*BBUF + (wc*32 + n*16 + fr)*64 + sx1]; } }
#define LDFA(b, p) {                                                          \
    fa[0][0] = *(const bf16x8*)&As[(b)*ABUF + (wr*128 + (2*(p)  )*16 + fr)*64 + sx0]; \
    fa[0][1] = *(const bf16x8*)&As[(b)*ABUF + (wr*128 + (2*(p)  )*16 + fr)*64 + sx1]; \
    fa[1][0] = *(const bf16x8*)&As[(b)*ABUF + (wr*128 + (2*(p)+1)*16 + fr)*64 + sx0]; \
    fa[1][1] = *(const bf16x8*)&As[(b)*ABUF + (wr*128 + (2*(p)+1)*16 + fr)*64 + sx1]; }
#define MM8(p) { __builtin_amdgcn_s_setprio(1);                               \
    _Pragma("unroll") for (int j = 0; j < 2; j++)                             \
    _Pragma("unroll") for (int n = 0; n < 2; n++) {                           \
      acc[2*(p)+j][n] = __builtin_amdgcn_mfma_f32_16x16x32_bf16(fa[j][0], fb[n][0], acc[2*(p)+j][n], 0, 0, 0); \
      acc[2*(p)+j][n] = __builtin_amdgcn_mfma_f32_16x16x32_bf16(fa[j][1], fb[n][1], acc[2*(p)+j][n], 0, 0, 0); } \
    __builtin_amdgcn_s_setprio(0); }
#define BARR  { __builtin_amdgcn_s_barrier(); __builtin_amdgcn_sched_barrier(0); }
#define LGKM0 asm volatile("s_waitcnt lgkmcnt(0)" ::: "memory");

  // prologue: stage tiles 0 and 1 fully (6 + 6 gloads)
  SAG(0,0,0); SAG(0,0,1); SAG(0,0,2); SAG(0,0,3); SBG(0,0,0); SBG(0,0,1);
  SAG(1,1,0); SAG(1,1,1); SAG(1,1,2); SAG(1,1,3); SBG(1,1,0); SBG(1,1,1);
  asm volatile("s_waitcnt vmcnt(6)" ::: "memory");   // tile 0 landed
  BARR;

  int cb = 0, b2 = 2;
  for (int t = 0; t < NT; ++t) {
    const bool st = (t + 2 < NT);
    // ph0
    LDFB(cb); LDFA(cb, 0);
    if (st) { SAG(t + 2, b2, 0); SAG(t + 2, b2, 1); }
    BARR; LGKM0; MM8(0); BARR;
    // ph1
    LDFA(cb, 1);
    if (st) { SAG(t + 2, b2, 2); SAG(t + 2, b2, 3); }
    BARR; LGKM0; MM8(1); BARR;
    // ph2
    LDFA(cb, 2);
    if (st) SBG(t + 2, b2, 0);
    BARR; LGKM0; MM8(2); BARR;
    // ph3
    LDFA(cb, 3);
    if (st) SBG(t + 2, b2, 1);
    BARR; LGKM0; MM8(3);
    if (t < NT - 1) {
      if (st) { asm volatile("s_waitcnt vmcnt(6)" ::: "memory"); }
      else    { asm volatile("s_waitcnt vmcnt(0)" ::: "memory"); }
      BARR;
    }
    cb = (cb == 2) ? 0 : cb + 1;
    b2 = (b2 == 2) ? 0 : b2 + 1;
  }
#undef SAG
#undef SBG
#undef LDFB
#undef LDFA
#undef MM8
#undef BARR
#undef LGKM0

  // epilogue: bias + fp32 resid, fp32 out (k_ln normalizes after)
  const int cr0 = lq * 4, cc = fr;
#pragma unroll
  for (int m = 0; m < 8; m++) {
#pragma unroll
    for (int n = 0; n < 2; n++) {
      long col = n0 + wc * 32 + n * 16 + cc;
      float bv = bias[col];
#pragma unroll
      for (int r = 0; r < 4; r++) {
        long row = m0 + wr * 128 + m * 16 + cr0 + r;
        Out[row * (long)N + col] = acc[m][n][r] + bv + resid[row * (long)N + col];
      }
    }
  }
}

// ---------------- LayerNorm over D=512, in place on d_out ----------------
__global__ __launch_bounds__(256) void k_ln(float* __restrict__ y,
                                            const float* __restrict__ lnw,
                                            const float* __restrict__ lnb) {
  int row = blockIdx.x, t = threadIdx.x;
  float2 v = ((const float2*)(y + (long)row * DM))[t];
  float s = v.x + v.y;
  float q = v.x * v.x + v.y * v.y;
  for (int off = 32; off; off >>= 1) { s += __shfl_down(s, off); q += __shfl_down(q, off); }
  __shared__ float ss[4], sq[4];
  int w = t >> 6, lane = t & 63;
  if (lane == 0) { ss[w] = s; sq[w] = q; }
  __syncthreads();
  if (t == 0) {
    float S = ss[0] + ss[1] + ss[2] + ss[3];
    float Q = sq[0] + sq[1] + sq[2] + sq[3];
    float mu = S / (float)DM;
    float var = Q / (float)DM - mu * mu;
    ss[0] = mu; sq[0] = rsqrtf(var + 1e-5f);
  }
  __syncthreads();
  float mu = ss[0], rstd = sq[0];
  float2 o;
  o.x = (v.x - mu) * rstd * lnw[2 * t]     + lnb[2 * t];
  o.y = (v.y - mu) * rstd * lnw[2 * t + 1] + lnb[2 * t + 1];
  ((float2*)(y + (long)row * DM))[t] = o;
}

// ---------------- launch ----------------
extern "C" void kernel_launch(void* const* d_in, const int* in_sizes, int n_in,
                              void* d_out, int out_size, void* d_ws, size_t ws_size,
                              hipStream_t stream) {
  (void)in_sizes; (void)n_in; (void)out_size; (void)ws_size;
  const float* x         = (const float*)d_in[0];
  const float* mask      = (const float*)d_in[1];
  const float* nu_log    = (const float*)d_in[2];
  const float* theta_log = (const float*)d_in[3];
  const float* gamma_log = (const float*)d_in[4];
  const float* W_in_r    = (const float*)d_in[5];
  const float* W_in_i    = (const float*)d_in[6];
  const float* b_in_r    = (const float*)d_in[7];
  const float* b_in_i    = (const float*)d_in[8];
  const float* W_out_r   = (const float*)d_in[9];
  const float* W_out_i   = (const float*)d_in[10];
  const float* b_out_r   = (const float*)d_in[11];
  const float* ln_w      = (const float*)d_in[13];
  const float* ln_b      = (const float*)d_in[14];

  char* ws = (char*)d_ws;
  unsigned short* ubuf = (unsigned short*)(ws);              // 67,108,864
  unsigned short* W1b  = (unsigned short*)(ws + 83886080);   // 2,097,152
  unsigned short* W2b  = (unsigned short*)(ws + 85983232);   // 2,097,152
  float*  b1   = (float*)(ws + 88080384);                    // 8,192
  float*  lam  = (float*)(ws + 88088576);                    // 8,192
  float2* Ebuf = (float2*)(ws + 88096768);                   // 1,048,576
  float2* Pbuf = (float2*)(ws + 89145344);                   // 1,048,576
  unsigned int* Ltab = (unsigned int*)(ws + 90193920);       // 524,288
  float*  Gm   = (float*)(ws + 90718208);                    // 65,536
  // total ws use: ~90.8 MB

  const int LDS1 = 3 * (256 + 128) * 32 * 2;                 // 73728 (gemm1_fused)
  const int LDS2 = 3 * (256 + 128) * 64 * 2;                 // 147456 (gemm2_8ph)
  hipFuncSetAttribute((const void*)gemm1_fused,
                      hipFuncAttributeMaxDynamicSharedMemorySize, LDS1);
  hipFuncSetAttribute((const void*)gemm2_8ph,
                      hipFuncAttributeMaxDynamicSharedMemorySize, LDS2);

  // merged prep (x-cvt removed)
  k_prep<<<8197, 256, 0, stream>>>(W_in_r, W_in_i, b_in_r, b_in_i, gamma_log,
                                   W_out_r, W_out_i, nu_log, theta_log, mask,
                                   W1b, b1, W2b, lam, Ltab, Gm);

  // GEMM1 (fp32-A reg-staged) + bias + full local scan
  gemm1_fused<<<1024, 256, LDS1, stream>>>(x, W1b, ubuf, b1, lam, mask, Ebuf);

  // chunk-carry scan -> P
  k_scan_carry<<<32, 256, 0, stream>>>(Ebuf, lam, Pbuf);

  // streaming carry correction: ubuf <- h (in place)
  k_corr<<<NROW / 2, 256, 0, stream>>>((unsigned int*)ubuf, Ltab, Pbuf, Gm);

  // GEMM2 (8-phase): out = h @ W2b^T + b_out + x -> fp32 d_out; 256 WGs
  gemm2_8ph<<<256, 512, LDS2, stream>>>(ubuf, W2b, (float*)d_out, b_out_r, x);

  // LayerNorm in place on d_out
  k_ln<<<NROW, 256, 0, stream>>>((float*)d_out, ln_w, ln_b);
}

// Round 13
// 164.359 us; speedup vs baseline: 1.4028x; 1.4028x over previous
//
#include <hip/hip_runtime.h>
#include <hip/hip_bf16.h>

// Problem constants
#define B_SZ 8
#define L_SZ 2048
#define DM   512
#define HIDC 1024            // complex hidden channels
#define NROW (B_SZ*L_SZ)     // 16384
#define NCOL (2*HIDC)        // 2048 (interleaved: col 2d = re_d, 2d+1 = im_d)
#define LCH  128             // scan chunk length
#define NCH  (L_SZ/LCH)      // 16 chunks

typedef __attribute__((ext_vector_type(8))) short bf16x8;
typedef __attribute__((ext_vector_type(4))) float f32x4;

typedef __attribute__((address_space(1))) const void gvoid_t;
typedef __attribute__((address_space(3))) void lvoid_t;

__device__ __forceinline__ void gload_lds16(const void* g, void* l) {
  __builtin_amdgcn_global_load_lds((gvoid_t*)g, (lvoid_t*)l, 16, 0, 0);
}

__device__ __forceinline__ unsigned short f2bf(float v) {
  return __builtin_bit_cast(unsigned short, __float2bfloat16(v));
}
__device__ __forceinline__ float bf2f(unsigned short u) {
  return __bfloat162float(__builtin_bit_cast(__hip_bfloat16, u));
}

// h_local(bf16 u32) + g * (Lambda(bf16 u32) (*) P(f32 pair)) -> bf16 u32
__device__ __forceinline__ unsigned int corr1(unsigned int h, unsigned int l,
                                              float pr, float pi, float g) {
  float hr = bf2f((unsigned short)(h & 0xffffu)), hi = bf2f((unsigned short)(h >> 16));
  float lr = bf2f((unsigned short)(l & 0xffffu)), li = bf2f((unsigned short)(l >> 16));
  float cr = g * (lr * pr - li * pi);
  float ci = g * (lr * pi + li * pr);
  return (unsigned int)f2bf(hr + cr) | ((unsigned int)f2bf(hi + ci) << 16);
}

// ---------------- merged prep + cvt kernel ----------------
__global__ void k_prep_cvt(const float* __restrict__ x,
                           const float* __restrict__ Wr,  const float* __restrict__ Wi,
                           const float* __restrict__ br,  const float* __restrict__ bi,
                           const float* __restrict__ gamma_log,
                           const float* __restrict__ Wor, const float* __restrict__ Woi,
                           const float* __restrict__ nu_log, const float* __restrict__ theta_log,
                           const float* __restrict__ mask,
                           unsigned short* __restrict__ xb,
                           unsigned short* __restrict__ W1b, float* __restrict__ b1,
                           unsigned short* __restrict__ W2b, float* __restrict__ lam,
                           unsigned int* __restrict__ Lt, float* __restrict__ Gm) {
  int bid = blockIdx.x, t = threadIdx.x;
  if (bid < 8192) {                       // cvt x -> bf16
    long i = (long)bid * 256 + t;
    float4 v = ((const float4*)x)[i];
    ushort4 o;
    o.x = f2bf(v.x); o.y = f2bf(v.y); o.z = f2bf(v.z); o.w = f2bf(v.w);
    ((ushort4*)xb)[i] = o;
  } else if (bid < 12288) {               // W1b[n][k], n=2d(+1)
    long idx = (long)(bid - 8192) * 256 + t;  // 2048*512
    int n = (int)(idx >> 9), k = (int)(idx & 511);
    int d = n >> 1;
    float g = __expf(gamma_log[d]);
    float w = (n & 1) ? Wi[(long)d * DM + k] : Wr[(long)d * DM + k];
    W1b[idx] = f2bf(g * w);
    if (k == 0) b1[n] = g * ((n & 1) ? bi[d] : br[d]);
  } else if (bid < 16384) {               // W2b[e][k], k=2d / 2d+1
    long idx = (long)(bid - 12288) * 256 + t; // 512*2048
    int e = (int)(idx >> 11), k = (int)(idx & 2047);
    int d = k >> 1;
    float w = (k & 1) ? -Woi[(long)e * HIDC + d] : Wor[(long)e * HIDC + d];
    W2b[idx] = f2bf(w);
  } else if (bid < 16388) {               // lam + Lambda table
    int d = (bid - 16384) * 256 + t;
    if (d < HIDC) {
      float nu = __expf(nu_log[d]);
      float th = __expf(theta_log[d]);
      float mag = __expf(-nu);
      float lr = mag * cosf(th), li = mag * sinf(th);
      lam[d]        = lr;
      lam[HIDC + d] = li;
      float ar = lr, ai = li;             // lam^{j+1}, j = 0..127
      for (int j = 0; j < 128; j++) {
        Lt[j * 1024 + d] = (unsigned int)f2bf(ar) | ((unsigned int)f2bf(ai) << 16);
        float nr = ar * lr - ai * li, ni = ar * li + ai * lr;
        ar = nr; ai = ni;
      }
    }
  } else {                                // Gm[b][l]
    if (t < 128) {
      int bb = t >> 4, cc = t & 15;
      int base2 = bb * 2048 + cc * 128;
      float G = (cc == 0) ? 0.f : mask[base2 - 1];
      Gm[base2] = G;
#pragma unroll 8
      for (int j = 1; j < 128; j++) {
        G *= mask[base2 + j - 1];
        Gm[base2 + j] = G;
      }
    }
  }
}

// ============ GEMM1 (v5 core) + fused FULL local-scan epilogue ============
// ubuf <- h_local (bf16, interleaved), E2 <- chunk-end values. (R9/R10/R11, verified)
__global__ __launch_bounds__(256, 2)
void gemm1_fused(const unsigned short* __restrict__ A, const unsigned short* __restrict__ Bw,
                 unsigned short* __restrict__ C, const float* __restrict__ bias,
                 const float* __restrict__ lam, const float* __restrict__ mask,
                 float2* __restrict__ E2) {
  constexpr int K = DM, N = NCOL;         // 512, 2048
  constexpr int ABUF = 256 * 32, BBUF = 128 * 32, NT = K / 32;  // NT=16
  extern __shared__ unsigned short lds[];
  unsigned short* As = lds;               // 3 * ABUF
  unsigned short* Bs = lds + 3 * ABUF;    // 3 * BBUF

  const int tid  = threadIdx.x;
  const int w    = tid >> 6, lane = tid & 63;
  const int wr   = w >> 1,   wc   = w & 1;
  const int fr   = lane & 15, lq  = lane >> 4;

  // XCD 2-D blocking: 1024 blocks = 64 mt x 16 nt, XCD owns 8 mt x all nt
  const int xcd  = blockIdx.x & 7;
  const int idx  = blockIdx.x >> 3;
  const int mt   = xcd * 8 + (idx >> 4);
  const int nt   = idx & 15;
  const long m0  = (long)mt * 256;
  const long n0  = (long)nt * 128;
  const int rot  = ((blockIdx.x >> 8) & 1) << 3;   // anti-phase K order

  const int srow  = tid >> 2;
  const int gslot = (tid & 3) ^ ((tid >> 3) & 3);
  const unsigned short* Agp = A  + (m0 + srow) * (long)K + gslot * 8;
  const unsigned short* Bgp = Bw + (n0 + srow) * (long)K + gslot * 8;
  const int ldst = tid * 8;

#define STAGE1(t, b) {                                                       \
    long ko = (long)(((t) + rot) & (NT - 1)) * 32;                           \
    _Pragma("unroll")                                                        \
    for (int u = 0; u < 4; u++)                                              \
      gload_lds16(Agp + ko + (long)(u * 64) * K,                             \
                  &As[(b) * ABUF + u * 2048 + ldst]);                        \
    gload_lds16(Bgp + ko,                  &Bs[(b) * BBUF +        ldst]);   \
    gload_lds16(Bgp + ko + (long)64 * K,   &Bs[(b) * BBUF + 2048 + ldst]); }

  const int sx = (lq ^ ((fr >> 1) & 3)) << 3;

  f32x4 acc[8][4] = {};

  STAGE1(0, 0);
  STAGE1(1, 1);
  asm volatile("s_waitcnt vmcnt(6)" ::: "memory");
  __builtin_amdgcn_s_barrier();
  __builtin_amdgcn_sched_barrier(0);

  int cb = 0, bt2 = 2;
  for (int t = 0; t < NT; ++t) {
    if (t + 2 < NT) STAGE1(t + 2, bt2);

    const unsigned short* Ab = As + cb * ABUF;
    const unsigned short* Bb = Bs + cb * BBUF;
    bf16x8 fa[8], fb[4];
#pragma unroll
    for (int m = 0; m < 8; m++)
      fa[m] = *(const bf16x8*)&Ab[(wr * 128 + m * 16 + fr) * 32 + sx];
#pragma unroll
    for (int n = 0; n < 4; n++)
      fb[n] = *(const bf16x8*)&Bb[(wc * 64 + n * 16 + fr) * 32 + sx];
    __builtin_amdgcn_s_setprio(1);
#pragma unroll
    for (int m = 0; m < 8; m++)
#pragma unroll
      for (int n = 0; n < 4; n++)
        acc[m][n] = __builtin_amdgcn_mfma_f32_16x16x32_bf16(fa[m], fb[n], acc[m][n], 0, 0, 0);
    __builtin_amdgcn_s_setprio(0);

    if (t < NT - 1) {
      if (t + 2 < NT) { asm volatile("s_waitcnt vmcnt(6)" ::: "memory"); }
      else            { asm volatile("s_waitcnt vmcnt(0)" ::: "memory"); }
      __builtin_amdgcn_s_barrier();
      __builtin_amdgcn_sched_barrier(0);
    }
    cb  = (cb  == 2) ? 0 : cb + 1;
    bt2 = (bt2 == 2) ? 0 : bt2 + 1;
  }
#undef STAGE1

  // ---- epilogue 1: bias-add, write bf16 tile to LDS [256][pitch 132]
  __syncthreads();
  const int cr0 = lq * 4, cc = fr;
#pragma unroll
  for (int m = 0; m < 8; m++) {
#pragma unroll
    for (int n = 0; n < 4; n++) {
      int coll = wc * 64 + n * 16 + cc;
      float bv = bias[n0 + coll];
#pragma unroll
      for (int r = 0; r < 4; r++) {
        int rowl = wr * 128 + m * 16 + cr0 + r;
        lds[rowl * 132 + coll] = f2bf(acc[m][n][r] + bv);
      }
    }
  }
  __syncthreads();

  // ---- preload mask slice to LDS scratch (after the tile)
  const int bidx = (int)(m0 >> 11);
  const int l0   = (int)(m0 & 2047);
  float* mbuf = (float*)(lds + 256 * 132);   // 256 floats
  mbuf[tid] = mask[bidx * L_SZ + l0 + tid];
  __syncthreads();

  // ---- epilogue 2: full local scan (128 threads)
  if (tid < 128) {
    const int chunk = tid >> 6, ch = tid & 63;
    const int dglob = (int)(n0 >> 1) + ch;
    const int cglob = (l0 >> 7) + chunk;
    const float lr = lam[dglob], li = lam[HIDC + dglob];
    const unsigned int* ldsw = (const unsigned int*)lds;
    unsigned int* Cw = (unsigned int*)C;
    const long crow0 = (m0 + chunk * 128) * (N / 2) + (n0 >> 1) + ch;
    float hr = 0.f, hi = 0.f;
    unsigned int v = ldsw[(chunk * 128) * 66 + ch];
    for (int j = 0; j < 128; j++) {
      unsigned int vn = (j < 127) ? ldsw[(chunk * 128 + j + 1) * 66 + ch] : 0u;
      float xr = bf2f((unsigned short)(v & 0xffffu));
      float xi = bf2f((unsigned short)(v >> 16));
      float g = (j > 0) ? mbuf[chunk * 128 + j - 1] : 0.f;   // chunk-local init
      float nr = xr + g * (lr * hr - li * hi);
      float ni = xi + g * (lr * hi + li * hr);
      hr = nr; hi = ni;
      Cw[crow0 + (long)j * (N / 2)] =
          (unsigned int)f2bf(hr) | ((unsigned int)f2bf(hi) << 16);
      v = vn;
    }
    E2[((long)bidx * NCH + cglob) * HIDC + dglob] = make_float2(hr, hi);
  }
}

// -------- scan pass 2: chunk-carry scan over E --------
__global__ void k_scan_carry(const float2* __restrict__ E2, const float* __restrict__ lam,
                             float2* __restrict__ P2) {
  int idx = blockIdx.x * 256 + threadIdx.x;   // 8192 = B * HIDC
  int b = idx >> 10, d = idx & (HIDC - 1);
  float lr = lam[d], li = lam[HIDC + d];
  float ar = lr, ai = li;                     // lam^128 via 7 squarings
  for (int s = 0; s < 7; s++) { float nr = ar * ar - ai * ai; float ni = 2.f * ar * ai; ar = nr; ai = ni; }
  float pr = 0.f, pi = 0.f;
  for (int c = 0; c < NCH; c++) {
    P2[((long)b * NCH + c) * HIDC + d] = make_float2(pr, pi);
    float2 e = E2[((long)b * NCH + c) * HIDC + d];
    float nr = e.x + ar * pr - ai * pi;
    float ni = e.y + ar * pi + ai * pr;
    pr = nr; pi = ni;
  }
}

// -------- carry correction (streaming, in place): h = h_local + Gm*(Lt (*) P) --------
__global__ __launch_bounds__(256)
void k_corr(unsigned int* __restrict__ u, const unsigned int* __restrict__ Lt,
            const float2* __restrict__ P2, const float* __restrict__ Gm) {
  const int t = threadIdx.x;
  const long row = (long)blockIdx.x * 2 + (t >> 7);
  const int d0 = (t & 127) * 8;
  const int j  = (int)(row & 127);
  const long bc = row >> 7;               // b*16 + c
  const float g = Gm[row];
  unsigned int* up = u + row * 1024 + d0;
  const unsigned int* lp = Lt + (long)j * 1024 + d0;
  const float2* pp = P2 + bc * 1024 + d0;
  uint4 h0 = *(const uint4*)up,        h1 = *(const uint4*)(up + 4);
  uint4 l0 = *(const uint4*)lp,        l1 = *(const uint4*)(lp + 4);
  float4 p0 = *(const float4*)pp,       p1 = *(const float4*)(pp + 2);
  float4 p2 = *(const float4*)(pp + 4), p3 = *(const float4*)(pp + 6);
  uint4 o0, o1;
  o0.x = corr1(h0.x, l0.x, p0.x, p0.y, g);
  o0.y = corr1(h0.y, l0.y, p0.z, p0.w, g);
  o0.z = corr1(h0.z, l0.z, p1.x, p1.y, g);
  o0.w = corr1(h0.w, l0.w, p1.z, p1.w, g);
  o1.x = corr1(h1.x, l1.x, p2.x, p2.y, g);
  o1.y = corr1(h1.y, l1.y, p2.z, p2.w, g);
  o1.z = corr1(h1.z, l1.z, p3.x, p3.y, g);
  o1.w = corr1(h1.w, l1.w, p3.z, p3.w, g);
  *(uint4*)up = o0;
  *(uint4*)(up + 4) = o1;
}

// ============ GEMM2: 8-phase counted-vmcnt schedule (T3+T4+T2+T5) ============
// out = h @ W2b^T + b_out + resid(bf16) -> fp32 (k_ln follows). (R11, verified)
__global__ __launch_bounds__(512, 1)
void gemm2_8ph(const unsigned short* __restrict__ A, const unsigned short* __restrict__ Bw,
               float* __restrict__ Out, const float* __restrict__ bias,
               const unsigned short* __restrict__ resid) {
  constexpr int K = NCOL, N = DM, NT = K / 64;   // 2048, 512, 32
  constexpr int ABUF = 256 * 64;   // 16384 ushorts (32KB)
  constexpr int BBUF = 128 * 64;   // 8192 ushorts (16KB)
  extern __shared__ unsigned short lds[];
  unsigned short* As = lds;              // 3 * ABUF
  unsigned short* Bs = lds + 3 * ABUF;   // 3 * BBUF

  const int tid = threadIdx.x;
  const int w = tid >> 6, lane = tid & 63;
  const int wr = w >> 2, wc = w & 3;     // 2M x 4N wave grid
  const int fr = lane & 15, lq = lane >> 4;

  // 256 blocks = 64 mt x 4 nt; XCD owns 8 mt x all nt
  const int xcd = blockIdx.x & 7;
  const int idx = blockIdx.x >> 3;       // 0..31
  const int mt  = xcd * 8 + (idx >> 2);
  const int nt  = idx & 3;
  const long m0 = (long)mt * 256, n0 = (long)nt * 128;

  // staging: 512 thr x 16B = 8KB = 64 rows(128B) per granule
  const int srow  = tid >> 3;            // 0..63
  const int gslot = (tid & 7) ^ ((tid >> 3) & 7);
  const unsigned short* Agp = A  + (m0 + srow) * (long)K + gslot * 8;
  const unsigned short* Bgp = Bw + (n0 + srow) * (long)K + gslot * 8;
  const int ldst = tid * 8;

#define SAG(t, b, g) gload_lds16(Agp + (long)(t) * 64 + (long)((g) * 64) * K, \
                                 &As[(b) * ABUF + (g) * 4096 + ldst])
#define SBG(t, b, g) gload_lds16(Bgp + (long)(t) * 64 + (long)((g) * 64) * K, \
                                 &Bs[(b) * BBUF + (g) * 4096 + ldst])

  const int sx0 = ((0 + lq) ^ (fr & 7)) << 3;
  const int sx1 = ((4 + lq) ^ (fr & 7)) << 3;

  bf16x8 fa[2][2], fb[2][2];
  f32x4 acc[8][2] = {};

#define LDFB(b) { _Pragma("unroll")                                           \
    for (int n = 0; n < 2; n++) {                                             \
      fb[n][0] = *(const bf16x8*)&Bs[(b)*BBUF + (wc*32 + n*16 + fr)*64 + sx0];\
      fb[n][1] = *(const bf16x8*)&Bs[(b)*BBUF + (wc*32 + n*16 + fr)*64 + sx1]; } }
#define LDFA(b, p) {                                                          \
    fa[0][0] = *(const bf16x8*)&As[(b)*ABUF + (wr*128 + (2*(p)  )*16 + fr)*64 + sx0]; \
    fa[0][1] = *(const bf16x8*)&As[(b)*ABUF + (wr*128 + (2*(p)  )*16 + fr)*64 + sx1]; \
    fa[1][0] = *(const bf16x8*)&As[(b)*ABUF + (wr*128 + (2*(p)+1)*16 + fr)*64 + sx0]; \
    fa[1][1] = *(const bf16x8*)&As[(b)*ABUF + (wr*128 + (2*(p)+1)*16 + fr)*64 + sx1]; }
#define MM8(p) { __builtin_amdgcn_s_setprio(1);                               \
    _Pragma("unroll") for (int j = 0; j < 2; j++)                             \
    _Pragma("unroll") for (int n = 0; n < 2; n++) {                           \
      acc[2*(p)+j][n] = __builtin_amdgcn_mfma_f32_16x16x32_bf16(fa[j][0], fb[n][0], acc[2*(p)+j][n], 0, 0, 0); \
      acc[2*(p)+j][n] = __builtin_amdgcn_mfma_f32_16x16x32_bf16(fa[j][1], fb[n][1], acc[2*(p)+j][n], 0, 0, 0); } \
    __builtin_amdgcn_s_setprio(0); }
#define BARR  { __builtin_amdgcn_s_barrier(); __builtin_amdgcn_sched_barrier(0); }
#define LGKM0 asm volatile("s_waitcnt lgkmcnt(0)" ::: "memory");

  // prologue: stage tiles 0 and 1 fully (6 + 6 gloads)
  SAG(0,0,0); SAG(0,0,1); SAG(0,0,2); SAG(0,0,3); SBG(0,0,0); SBG(0,0,1);
  SAG(1,1,0); SAG(1,1,1); SAG(1,1,2); SAG(1,1,3); SBG(1,1,0); SBG(1,1,1);
  asm volatile("s_waitcnt vmcnt(6)" ::: "memory");   // tile 0 landed
  BARR;

  int cb = 0, b2 = 2;
  for (int t = 0; t < NT; ++t) {
    const bool st = (t + 2 < NT);
    // ph0
    LDFB(cb); LDFA(cb, 0);
    if (st) { SAG(t + 2, b2, 0); SAG(t + 2, b2, 1); }
    BARR; LGKM0; MM8(0); BARR;
    // ph1
    LDFA(cb, 1);
    if (st) { SAG(t + 2, b2, 2); SAG(t + 2, b2, 3); }
    BARR; LGKM0; MM8(1); BARR;
    // ph2
    LDFA(cb, 2);
    if (st) SBG(t + 2, b2, 0);
    BARR; LGKM0; MM8(2); BARR;
    // ph3
    LDFA(cb, 3);
    if (st) SBG(t + 2, b2, 1);
    BARR; LGKM0; MM8(3);
    if (t < NT - 1) {
      if (st) { asm volatile("s_waitcnt vmcnt(6)" ::: "memory"); }
      else    { asm volatile("s_waitcnt vmcnt(0)" ::: "memory"); }
      BARR;
    }
    cb = (cb == 2) ? 0 : cb + 1;
    b2 = (b2 == 2) ? 0 : b2 + 1;
  }
#undef SAG
#undef SBG
#undef LDFB
#undef LDFA
#undef MM8
#undef BARR
#undef LGKM0

  // epilogue: bias + resid, fp32 out (k_ln normalizes after)
  const int cr0 = lq * 4, cc = fr;
#pragma unroll
  for (int m = 0; m < 8; m++) {
#pragma unroll
    for (int n = 0; n < 2; n++) {
      long col = n0 + wc * 32 + n * 16 + cc;
      float bv = bias[col];
#pragma unroll
      for (int r = 0; r < 4; r++) {
        long row = m0 + wr * 128 + m * 16 + cr0 + r;
        Out[row * (long)N + col] = acc[m][n][r] + bv + bf2f(resid[row * (long)N + col]);
      }
    }
  }
}

// ---------------- LayerNorm over D=512, in place on d_out ----------------
__global__ __launch_bounds__(256) void k_ln(float* __restrict__ y,
                                            const float* __restrict__ lnw,
                                            const float* __restrict__ lnb) {
  int row = blockIdx.x, t = threadIdx.x;
  float2 v = ((const float2*)(y + (long)row * DM))[t];
  float s = v.x + v.y;
  float q = v.x * v.x + v.y * v.y;
  for (int off = 32; off; off >>= 1) { s += __shfl_down(s, off); q += __shfl_down(q, off); }
  __shared__ float ss[4], sq[4];
  int w = t >> 6, lane = t & 63;
  if (lane == 0) { ss[w] = s; sq[w] = q; }
  __syncthreads();
  if (t == 0) {
    float S = ss[0] + ss[1] + ss[2] + ss[3];
    float Q = sq[0] + sq[1] + sq[2] + sq[3];
    float mu = S / (float)DM;
    float var = Q / (float)DM - mu * mu;
    ss[0] = mu; sq[0] = rsqrtf(var + 1e-5f);
  }
  __syncthreads();
  float mu = ss[0], rstd = sq[0];
  float2 o;
  o.x = (v.x - mu) * rstd * lnw[2 * t]     + lnb[2 * t];
  o.y = (v.y - mu) * rstd * lnw[2 * t + 1] + lnb[2 * t + 1];
  ((float2*)(y + (long)row * DM))[t] = o;
}

// ---------------- launch ----------------
extern "C" void kernel_launch(void* const* d_in, const int* in_sizes, int n_in,
                              void* d_out, int out_size, void* d_ws, size_t ws_size,
                              hipStream_t stream) {
  (void)in_sizes; (void)n_in; (void)out_size; (void)ws_size;
  const float* x         = (const float*)d_in[0];
  const float* mask      = (const float*)d_in[1];
  const float* nu_log    = (const float*)d_in[2];
  const float* theta_log = (const float*)d_in[3];
  const float* gamma_log = (const float*)d_in[4];
  const float* W_in_r    = (const float*)d_in[5];
  const float* W_in_i    = (const float*)d_in[6];
  const float* b_in_r    = (const float*)d_in[7];
  const float* b_in_i    = (const float*)d_in[8];
  const float* W_out_r   = (const float*)d_in[9];
  const float* W_out_i   = (const float*)d_in[10];
  const float* b_out_r   = (const float*)d_in[11];
  const float* ln_w      = (const float*)d_in[13];
  const float* ln_b      = (const float*)d_in[14];

  char* ws = (char*)d_ws;
  unsigned short* ubuf = (unsigned short*)(ws);              // 67,108,864
  unsigned short* xb   = (unsigned short*)(ws + 67108864);   // 16,777,216
  unsigned short* W1b  = (unsigned short*)(ws + 83886080);   // 2,097,152
  unsigned short* W2b  = (unsigned short*)(ws + 85983232);   // 2,097,152
  float*  b1   = (float*)(ws + 88080384);                    // 8,192
  float*  lam  = (float*)(ws + 88088576);                    // 8,192
  float2* Ebuf = (float2*)(ws + 88096768);                   // 1,048,576
  float2* Pbuf = (float2*)(ws + 89145344);                   // 1,048,576
  unsigned int* Ltab = (unsigned int*)(ws + 90193920);       // 524,288
  float*  Gm   = (float*)(ws + 90718208);                    // 65,536
  // total ws use: ~90.8 MB

  const int LDS1 = 3 * (256 + 128) * 32 * 2;                 // 73728 (gemm1_fused)
  const int LDS2 = 3 * (256 + 128) * 64 * 2;                 // 147456 (gemm2_8ph)
  hipFuncSetAttribute((const void*)gemm1_fused,
                      hipFuncAttributeMaxDynamicSharedMemorySize, LDS1);
  hipFuncSetAttribute((const void*)gemm2_8ph,
                      hipFuncAttributeMaxDynamicSharedMemorySize, LDS2);

  // merged prep + cvt (one launch)
  k_prep_cvt<<<16389, 256, 0, stream>>>(x, W_in_r, W_in_i, b_in_r, b_in_i,
                                        gamma_log, W_out_r, W_out_i,
                                        nu_log, theta_log, mask,
                                        xb, W1b, b1, W2b, lam, Ltab, Gm);

  // GEMM1 + bias + full local scan: ubuf <- h_local, Ebuf <- chunk ends
  gemm1_fused<<<1024, 256, LDS1, stream>>>(xb, W1b, ubuf, b1, lam, mask, Ebuf);

  // chunk-carry scan -> P
  k_scan_carry<<<32, 256, 0, stream>>>(Ebuf, lam, Pbuf);

  // streaming carry correction: ubuf <- h (in place)
  k_corr<<<NROW / 2, 256, 0, stream>>>((unsigned int*)ubuf, Ltab, Pbuf, Gm);

  // GEMM2 (8-phase): out = h @ W2b^T + b_out + xb -> fp32 d_out; 256 WGs
  gemm2_8ph<<<256, 512, LDS2, stream>>>(ubuf, W2b, (float*)d_out, b_out_r, xb);

  // LayerNorm in place on d_out
  k_ln<<<NROW, 256, 0, stream>>>((float*)d_out, ln_w, ln_b);
}